// Round 5
// baseline (84.392 us; speedup 1.0000x reference)
//
#include <hip/hip_runtime.h>
#include <hip/hip_bf16.h>
#include <stdint.h>

typedef __attribute__((ext_vector_type(4))) float  f32x4;
typedef __attribute__((ext_vector_type(8))) short  s16x8;
typedef __attribute__((ext_vector_type(4))) int    i32x4;
typedef __attribute__((ext_vector_type(8))) unsigned short u16x8;

#define NN 4096
#define GT_LD 4096
#define NUM_STRIDE (4096 * 512)

__device__ __forceinline__ unsigned short f2bf(float f) {
  uint32_t u = __builtin_bit_cast(uint32_t, f);
  u += 0x7FFF + ((u >> 16) & 1);           // RNE
  return (unsigned short)(u >> 16);
}

__device__ __forceinline__ void gload_lds16(const void* g, void* l) {
  __builtin_amdgcn_global_load_lds(
      (const __attribute__((address_space(1))) unsigned int*)g,
      (__attribute__((address_space(3))) unsigned int*)l, 16, 0, 0);
}

// ---- kernel A: conv_x + conv_wt fused (block ranges) --------------------
__global__ __launch_bounds__(512) void k_small(const float* __restrict__ x,
                                               const float* __restrict__ W,
                                               unsigned short* __restrict__ xb,
                                               unsigned short* __restrict__ wt) {
  int bid = blockIdx.x;
  if (bid < 512) {                          // x f32 -> bf16, 4/thread
    int t = bid * 512 + threadIdx.x;
    f32x4 v = ((const f32x4*)x)[t];
    uint64_t r = (uint64_t)f2bf(v.x) | ((uint64_t)f2bf(v.y) << 16) |
                 ((uint64_t)f2bf(v.z) << 32) | ((uint64_t)f2bf(v.w) << 48);
    ((uint64_t*)xb)[t] = r;
  } else {                                  // W (256x512) -> W^T (512x256) bf16
    int t = (bid - 512) * 512 + threadIdx.x;
    int c = t >> 8, k = t & 255;
    wt[t] = f2bf(W[k * 512 + c]);
  }
}

// ---- kernel B: fat kernel — h_gt blocks [0,256) + adj-conv blocks -------
__global__ __launch_bounds__(512) void k_fat(const int* __restrict__ adj,
                                             unsigned short* __restrict__ ab,
                                             const unsigned short* __restrict__ xb,
                                             const unsigned short* __restrict__ wt,
                                             const float* __restrict__ attn,
                                             unsigned short* __restrict__ gt) {
  __shared__ unsigned short lx[16 * 256];   // [16 rows][512B], XOR-swizzled
  __shared__ unsigned short lw[512 * 64];   // [512 cols][128B], XOR-swizzled

  if (blockIdx.x >= 256) {                  // ---- adj int32 -> bf16, 8/thread
    int t = (blockIdx.x - 256) * 512 + threadIdx.x;
    const i32x4* p = (const i32x4*)adj;
    i32x4 v0 = p[2 * t], v1 = p[2 * t + 1];
    u16x8 r;
    r[0] = v0.x ? 0x3F80 : 0; r[1] = v0.y ? 0x3F80 : 0;
    r[2] = v0.z ? 0x3F80 : 0; r[3] = v0.w ? 0x3F80 : 0;
    r[4] = v1.x ? 0x3F80 : 0; r[5] = v1.y ? 0x3F80 : 0;
    r[6] = v1.z ? 0x3F80 : 0; r[7] = v1.w ? 0x3F80 : 0;
    ((u16x8*)ab)[t] = r;
    return;
  }

  // ---- h = x@W tile, s_dst, w = exp, write G^T (rows 0..519) ----
  const int tid = threadIdx.x;
  const int lane = tid & 63;
  const int h = tid >> 6;
  const int l15 = lane & 15, lg = lane >> 4;
  const int j0 = blockIdx.x * 16;

  {  // stage x tile once (16 rows x 512B), pre-permuted source
    int L = tid * 16;
    int row = L >> 9, b = L & 511;
    int sb = b ^ ((row & 7) << 4);
    gload_lds16((const char*)xb + (j0 + row) * 512 + sb, (char*)lx + L);
  }

  f32x4 acc[4] = {};
  for (int kc = 0; kc < 4; ++kc) {          // K chunks of 64
#pragma unroll
    for (int i = 0; i < 8; ++i) {           // stage W^T chunk [512 cols][128B]
      int L = (i * 512 + tid) * 16;
      int c = L >> 7, b = L & 127;
      int sb = b ^ ((c & 7) << 4);
      gload_lds16((const char*)wt + c * 512 + kc * 128 + sb, (char*)lw + L);
    }
    asm volatile("s_waitcnt vmcnt(0)");
    __syncthreads();
#pragma unroll
    for (int kk = 0; kk < 2; ++kk) {
      int kby = kk * 64 + lg * 16;
      s16x8 a = *(const s16x8*)((const char*)lx + l15 * 512 +
                                ((kc * 128 + kby) ^ ((l15 & 7) << 4)));
#pragma unroll
      for (int n = 0; n < 4; ++n) {
        int c = h * 64 + n * 16 + l15;
        s16x8 b = *(const s16x8*)((const char*)lw + c * 128 + (kby ^ ((c & 7) << 4)));
        acc[n] = __builtin_amdgcn_mfma_f32_16x16x32_bf16(a, b, acc[n], 0, 0, 0);
      }
    }
    __syncthreads();
  }

  float adv[4];
#pragma unroll
  for (int n = 0; n < 4; ++n) adv[n] = attn[h * 128 + 64 + n * 16 + l15];
#pragma unroll
  for (int r = 0; r < 4; ++r) {
    float p = acc[0][r] * adv[0] + acc[1][r] * adv[1] +
              acc[2][r] * adv[2] + acc[3][r] * adv[3];
#pragma unroll
    for (int m = 1; m < 16; m <<= 1) p += __shfl_xor(p, m);
    float w = expf(p);
    int node = j0 + lg * 4 + r;
#pragma unroll
    for (int n = 0; n < 4; ++n) {
      int c = h * 64 + n * 16 + l15;
      gt[c * GT_LD + node] = f2bf(acc[n][r] * w);
    }
    if (l15 == 0) gt[(512 + h) * GT_LD + node] = f2bf(w);
  }
}

// ---- kernel C: numer = adj_bf16 @ G, split-K, 3-deep counted pipeline ---
// BM=128 BN=64 BK=64, 4 waves (each 64x32), LDS 72KB (3 bufs), grid (288,S).
// Counted vmcnt(12): stages kt+1/kt+2 stay in flight across barriers (T3/T4).
// GT rows 520..575 are stale; they only feed discarded output columns.
__global__ __launch_bounds__(256) void k_gemm(const unsigned short* __restrict__ A,
                                              const unsigned short* __restrict__ GT,
                                              float* __restrict__ out,
                                              float* __restrict__ numx,
                                              float* __restrict__ den,
                                              int klen) {
  __shared__ unsigned short lA[3][128 * 64];   // 16KB each
  __shared__ unsigned short lB[3][64 * 64];    // 8KB each
  const int tid = threadIdx.x;
  const int lane = tid & 63, wid = tid >> 6;
  const int wr = wid >> 1, wc = wid & 1;
  const int l15 = lane & 15, lg = lane >> 4;

  int g = blockIdx.x;                       // 288 = 8*36 bijective XCD swizzle
  int swz = (g & 7) * 36 + (g >> 3);
  int bx = swz / 9, by = swz % 9;
  const int row0 = bx * 128, c0 = by * 64;

  const int s = blockIdx.y;
  float* num = (s == 0) ? out : (numx + (s - 1) * NUM_STRIDE);
  float* dens = den + s * (4096 * 8);

  const char* Abase = (const char*)A + row0 * 8192 + (long)s * klen * 2;
  const char* Bbase = (const char*)GT + c0 * 8192 + (long)s * klen * 2;

  auto stageA = [&](unsigned short* dst, int kt) {   // 4 gload_lds / thread
#pragma unroll
    for (int i = 0; i < 4; ++i) {
      int L = (i * 256 + tid) * 16;
      int r = L >> 7, b = L & 127;
      int sb = b ^ ((r & 7) << 4);
      gload_lds16(Abase + r * 8192 + kt * 128 + sb, (char*)dst + L);
    }
  };
  auto stageB = [&](unsigned short* dst, int kt) {   // 2 gload_lds / thread
#pragma unroll
    for (int i = 0; i < 2; ++i) {
      int L = (i * 256 + tid) * 16;
      int r = L >> 7, b = L & 127;
      int sb = b ^ ((r & 7) << 4);
      gload_lds16(Bbase + r * 8192 + kt * 128 + sb, (char*)dst + L);
    }
  };

  f32x4 acc[4][2] = {};
  const int NKT = klen >> 6;

  // prologue: 2 tiles in flight (12 outstanding vmem / wave)
  stageA(lA[0], 0); stageB(lB[0], 0);
  stageA(lA[1], 1); stageB(lB[1], 1);

  int cur = 0;
  for (int kt = 0; kt < NKT; ++kt) {
    int pf = cur + 2; if (pf >= 3) pf -= 3;
    if (kt < NKT - 2) {
      stageA(lA[pf], kt + 2);               // issue: 18 outstanding
      stageB(lB[pf], kt + 2);
      asm volatile("s_waitcnt vmcnt(12)" ::: "memory");  // stage(kt) landed
    } else if (kt == NKT - 2) {
      asm volatile("s_waitcnt vmcnt(6)" ::: "memory");
    } else {
      asm volatile("s_waitcnt vmcnt(0)" ::: "memory");
    }
    __builtin_amdgcn_s_barrier();           // all waves' stage(kt) complete

    __builtin_amdgcn_s_setprio(1);
#pragma unroll
    for (int kk = 0; kk < 2; ++kk) {
      int kby = kk * 64 + lg * 16;
      s16x8 a[4], b[2];
#pragma unroll
      for (int m = 0; m < 4; ++m) {
        int r = wr * 64 + m * 16 + l15;
        a[m] = *(const s16x8*)((const char*)lA[cur] + r * 128 + (kby ^ ((r & 7) << 4)));
      }
#pragma unroll
      for (int n = 0; n < 2; ++n) {
        int c = wc * 32 + n * 16 + l15;
        b[n] = *(const s16x8*)((const char*)lB[cur] + c * 128 + (kby ^ ((c & 7) << 4)));
      }
#pragma unroll
      for (int m = 0; m < 4; ++m)
#pragma unroll
        for (int n = 0; n < 2; ++n)
          acc[m][n] = __builtin_amdgcn_mfma_f32_16x16x32_bf16(a[m], b[n], acc[m][n], 0, 0, 0);
    }
    __builtin_amdgcn_s_setprio(0);

    asm volatile("s_waitcnt lgkmcnt(0)" ::: "memory");   // ds_reads drained
    __builtin_amdgcn_sched_barrier(0);
    __builtin_amdgcn_s_barrier();           // buf[cur] now safe to overwrite
    cur = cur + 1; if (cur == 3) cur = 0;
  }

#pragma unroll
  for (int m = 0; m < 4; ++m)
#pragma unroll
    for (int n = 0; n < 2; ++n) {
      int c = c0 + wc * 32 + n * 16 + l15;
#pragma unroll
      for (int r = 0; r < 4; ++r) {
        int i = row0 + wr * 64 + m * 16 + lg * 4 + r;
        float v = acc[m][n][r];
        if (c < 512) num[i * 512 + c] = v;
        else if (c < 520) dens[i * 8 + (c - 512)] = v;
      }
    }
}

// ---- kernel D: out = (sum of split numerators) / (sum of split denoms) --
__global__ __launch_bounds__(256) void k_final(float* __restrict__ out,
                                               const float* __restrict__ numx,
                                               const float* __restrict__ den,
                                               int S) {
  int t = blockIdx.x * 256 + threadIdx.x;   // one float4 / thread
  int i = t >> 7, h = (t >> 4) & 7;
  f32x4 v = ((const f32x4*)out)[t];
  float d = den[i * 8 + h];
  for (int s = 1; s < S; ++s) {
    f32x4 u = ((const f32x4*)(numx + (s - 1) * NUM_STRIDE))[t];
    v.x += u.x; v.y += u.y; v.z += u.z; v.w += u.w;
    d += den[s * 4096 * 8 + i * 8 + h];
  }
  v.x /= d; v.y /= d; v.z /= d; v.w /= d;
  ((f32x4*)out)[t] = v;
}

extern "C" void kernel_launch(void* const* d_in, const int* in_sizes, int n_in,
                              void* d_out, int out_size, void* d_ws, size_t ws_size,
                              hipStream_t stream) {
  const float* x    = (const float*)d_in[0];
  const int*   adj  = (const int*)d_in[1];
  const float* W    = (const float*)d_in[2];
  const float* attn = (const float*)d_in[3];
  float* out = (float*)d_out;
  char* ws = (char*)d_ws;

  // ws layout
  unsigned short* Ab  = (unsigned short*)(ws);                 // 32 MB   adj bf16
  unsigned short* GTp = (unsigned short*)(ws + 33554432);      // 4.5 MB  G^T
  unsigned short* XB  = (unsigned short*)(ws + 38273024);      // 2 MB    x bf16
  unsigned short* WT  = (unsigned short*)(ws + 40370176);      // 256 KB  W^T bf16
  float*          DEN = (float*)(ws + 40632320);               // 512 KB  denom (4 splits)
  float*          NUMX = (float*)(ws + 41156608);              // up to 24 MB partials

  int S = 1;
  if (ws_size >= 41156608ull + 3ull * NUM_STRIDE * 4 + 65536) S = 4;
  else if (ws_size >= 41156608ull + 1ull * NUM_STRIDE * 4 + 65536) S = 2;

  k_small<<<768, 512, 0, stream>>>(x, W, XB, WT);
  k_fat  <<<4352, 512, 0, stream>>>(adj, Ab, XB, WT, attn, GTp);
  dim3 ggrid(288, S);
  k_gemm <<<ggrid, 256, 0, stream>>>(Ab, GTp, out, NUMX, DEN, 4096 / S);
  k_final<<<2048, 256, 0, stream>>>(out, NUMX, DEN, S);
}

// Round 6
// 66.981 us; speedup vs baseline: 1.2599x; 1.2599x over previous
//
#include <hip/hip_runtime.h>
#include <hip/hip_bf16.h>
#include <stdint.h>

typedef __attribute__((ext_vector_type(4))) float  f32x4;
typedef __attribute__((ext_vector_type(8))) short  s16x8;
typedef __attribute__((ext_vector_type(4))) int    i32x4;
typedef __attribute__((ext_vector_type(8))) unsigned short u16x8;

#define NN 4096
#define GT_LD 4096
#define NUM_STRIDE (4096 * 512)

__device__ __forceinline__ unsigned short f2bf(float f) {
  uint32_t u = __builtin_bit_cast(uint32_t, f);
  u += 0x7FFF + ((u >> 16) & 1);           // RNE
  return (unsigned short)(u >> 16);
}

__device__ __forceinline__ void gload_lds16(const void* g, void* l) {
  __builtin_amdgcn_global_load_lds(
      (const __attribute__((address_space(1))) unsigned int*)g,
      (__attribute__((address_space(3))) unsigned int*)l, 16, 0, 0);
}

// ---- kernel A: conv_x + conv_wt fused (block ranges) --------------------
__global__ __launch_bounds__(512) void k_small(const float* __restrict__ x,
                                               const float* __restrict__ W,
                                               unsigned short* __restrict__ xb,
                                               unsigned short* __restrict__ wt) {
  int bid = blockIdx.x;
  if (bid < 512) {                          // x f32 -> bf16, 4/thread
    int t = bid * 512 + threadIdx.x;
    f32x4 v = ((const f32x4*)x)[t];
    uint64_t r = (uint64_t)f2bf(v.x) | ((uint64_t)f2bf(v.y) << 16) |
                 ((uint64_t)f2bf(v.z) << 32) | ((uint64_t)f2bf(v.w) << 48);
    ((uint64_t*)xb)[t] = r;
  } else {                                  // W (256x512) -> W^T (512x256) bf16
    int t = (bid - 512) * 512 + threadIdx.x;
    int c = t >> 8, k = t & 255;
    wt[t] = f2bf(W[k * 512 + c]);
  }
}

// ---- kernel B: fat kernel — h_gt blocks [0,256) + adj-conv blocks -------
__global__ __launch_bounds__(512) void k_fat(const int* __restrict__ adj,
                                             unsigned short* __restrict__ ab,
                                             const unsigned short* __restrict__ xb,
                                             const unsigned short* __restrict__ wt,
                                             const float* __restrict__ attn,
                                             unsigned short* __restrict__ gt) {
  __shared__ unsigned short lx[16 * 256];   // [16 rows][512B], XOR-swizzled
  __shared__ unsigned short lw[512 * 64];   // [512 cols][128B], XOR-swizzled

  if (blockIdx.x >= 256) {                  // ---- adj int32 -> bf16, 8/thread
    int t = (blockIdx.x - 256) * 512 + threadIdx.x;
    const i32x4* p = (const i32x4*)adj;
    i32x4 v0 = p[2 * t], v1 = p[2 * t + 1];
    u16x8 r;
    r[0] = v0.x ? 0x3F80 : 0; r[1] = v0.y ? 0x3F80 : 0;
    r[2] = v0.z ? 0x3F80 : 0; r[3] = v0.w ? 0x3F80 : 0;
    r[4] = v1.x ? 0x3F80 : 0; r[5] = v1.y ? 0x3F80 : 0;
    r[6] = v1.z ? 0x3F80 : 0; r[7] = v1.w ? 0x3F80 : 0;
    ((u16x8*)ab)[t] = r;
    return;
  }

  // ---- h = x@W tile, s_dst, w = exp, write G^T (rows 0..519) ----
  const int tid = threadIdx.x;
  const int lane = tid & 63;
  const int h = tid >> 6;
  const int l15 = lane & 15, lg = lane >> 4;
  const int j0 = blockIdx.x * 16;

  {  // stage x tile once (16 rows x 512B), pre-permuted source
    int L = tid * 16;
    int row = L >> 9, b = L & 511;
    int sb = b ^ ((row & 7) << 4);
    gload_lds16((const char*)xb + (j0 + row) * 512 + sb, (char*)lx + L);
  }

  f32x4 acc[4] = {};
  for (int kc = 0; kc < 4; ++kc) {          // K chunks of 64
#pragma unroll
    for (int i = 0; i < 8; ++i) {           // stage W^T chunk [512 cols][128B]
      int L = (i * 512 + tid) * 16;
      int c = L >> 7, b = L & 127;
      int sb = b ^ ((c & 7) << 4);
      gload_lds16((const char*)wt + c * 512 + kc * 128 + sb, (char*)lw + L);
    }
    asm volatile("s_waitcnt vmcnt(0)");
    __syncthreads();
#pragma unroll
    for (int kk = 0; kk < 2; ++kk) {
      int kby = kk * 64 + lg * 16;
      s16x8 a = *(const s16x8*)((const char*)lx + l15 * 512 +
                                ((kc * 128 + kby) ^ ((l15 & 7) << 4)));
#pragma unroll
      for (int n = 0; n < 4; ++n) {
        int c = h * 64 + n * 16 + l15;
        s16x8 b = *(const s16x8*)((const char*)lw + c * 128 + (kby ^ ((c & 7) << 4)));
        acc[n] = __builtin_amdgcn_mfma_f32_16x16x32_bf16(a, b, acc[n], 0, 0, 0);
      }
    }
    __syncthreads();
  }

  float adv[4];
#pragma unroll
  for (int n = 0; n < 4; ++n) adv[n] = attn[h * 128 + 64 + n * 16 + l15];
#pragma unroll
  for (int r = 0; r < 4; ++r) {
    float p = acc[0][r] * adv[0] + acc[1][r] * adv[1] +
              acc[2][r] * adv[2] + acc[3][r] * adv[3];
#pragma unroll
    for (int m = 1; m < 16; m <<= 1) p += __shfl_xor(p, m);
    float w = expf(p);
    int node = j0 + lg * 4 + r;
#pragma unroll
    for (int n = 0; n < 4; ++n) {
      int c = h * 64 + n * 16 + l15;
      gt[c * GT_LD + node] = f2bf(acc[n][r] * w);
    }
    if (l15 == 0) gt[(512 + h) * GT_LD + node] = f2bf(w);
  }
}

// ---- kernel C: numer = adj_bf16 @ G, split-K ----------------------------
// BM=128 BN=64 BK=64, 4 waves (each 64x32), SINGLE-buffer LDS 24KB (m97
// 2-barrier structure) -> 5 blocks/CU resident. grid (288, S).
// GT rows 520..575 are stale; they only feed discarded output columns.
__global__ __launch_bounds__(256, 5) void k_gemm(const unsigned short* __restrict__ A,
                                                 const unsigned short* __restrict__ GT,
                                                 float* __restrict__ out,
                                                 float* __restrict__ numx,
                                                 float* __restrict__ den,
                                                 int klen) {
  __shared__ unsigned short lA[128 * 64];   // 16KB
  __shared__ unsigned short lB[64 * 64];    // 8KB
  const int tid = threadIdx.x;
  const int lane = tid & 63, wid = tid >> 6;
  const int wr = wid >> 1, wc = wid & 1;
  const int l15 = lane & 15, lg = lane >> 4;

  int g = blockIdx.x;                       // 288 = 8*36 bijective XCD swizzle
  int swz = (g & 7) * 36 + (g >> 3);
  int bx = swz / 9, by = swz % 9;
  const int row0 = bx * 128, c0 = by * 64;

  const int s = blockIdx.y;
  float* num = (s == 0) ? out : (numx + (s - 1) * NUM_STRIDE);
  float* dens = den + s * (4096 * 8);

  const char* Abase = (const char*)A + row0 * 8192 + (long)s * klen * 2;
  const char* Bbase = (const char*)GT + c0 * 8192 + (long)s * klen * 2;

  auto stageA = [&](int kt) {               // 4 gload_lds / thread
#pragma unroll
    for (int i = 0; i < 4; ++i) {
      int L = (i * 256 + tid) * 16;
      int r = L >> 7, b = L & 127;
      int sb = b ^ ((r & 7) << 4);
      gload_lds16(Abase + r * 8192 + kt * 128 + sb, (char*)lA + L);
    }
  };
  auto stageB = [&](int kt) {               // 2 gload_lds / thread
#pragma unroll
    for (int i = 0; i < 2; ++i) {
      int L = (i * 256 + tid) * 16;
      int r = L >> 7, b = L & 127;
      int sb = b ^ ((r & 7) << 4);
      gload_lds16(Bbase + r * 8192 + kt * 128 + sb, (char*)lB + L);
    }
  };

  f32x4 acc[4][2] = {};
  const int NKT = klen >> 6;

  for (int kt = 0; kt < NKT; ++kt) {
    stageA(kt);
    stageB(kt);
    __syncthreads();                        // drains vmcnt: tile resident
#pragma unroll
    for (int kk = 0; kk < 2; ++kk) {
      int kby = kk * 64 + lg * 16;
      s16x8 a[4], b[2];
#pragma unroll
      for (int m = 0; m < 4; ++m) {
        int r = wr * 64 + m * 16 + l15;
        a[m] = *(const s16x8*)((const char*)lA + r * 128 + (kby ^ ((r & 7) << 4)));
      }
#pragma unroll
      for (int n = 0; n < 2; ++n) {
        int c = wc * 32 + n * 16 + l15;
        b[n] = *(const s16x8*)((const char*)lB + c * 128 + (kby ^ ((c & 7) << 4)));
      }
#pragma unroll
      for (int m = 0; m < 4; ++m)
#pragma unroll
        for (int n = 0; n < 2; ++n)
          acc[m][n] = __builtin_amdgcn_mfma_f32_16x16x32_bf16(a[m], b[n], acc[m][n], 0, 0, 0);
    }
    __syncthreads();                        // reads done: safe to overwrite
  }

#pragma unroll
  for (int m = 0; m < 4; ++m)
#pragma unroll
    for (int n = 0; n < 2; ++n) {
      int c = c0 + wc * 32 + n * 16 + l15;
#pragma unroll
      for (int r = 0; r < 4; ++r) {
        int i = row0 + wr * 64 + m * 16 + lg * 4 + r;
        float v = acc[m][n][r];
        if (c < 512) num[i * 512 + c] = v;
        else if (c < 520) dens[i * 8 + (c - 512)] = v;
      }
    }
}

// ---- kernel D: out = (sum of split numerators) / (sum of split denoms) --
__global__ __launch_bounds__(256) void k_final(float* __restrict__ out,
                                               const float* __restrict__ numx,
                                               const float* __restrict__ den,
                                               int S) {
  int t = blockIdx.x * 256 + threadIdx.x;   // one float4 / thread
  int i = t >> 7, h = (t >> 4) & 7;
  f32x4 v = ((const f32x4*)out)[t];
  float d = den[i * 8 + h];
  for (int s = 1; s < S; ++s) {
    f32x4 u = ((const f32x4*)(numx + (s - 1) * NUM_STRIDE))[t];
    v.x += u.x; v.y += u.y; v.z += u.z; v.w += u.w;
    d += den[s * 4096 * 8 + i * 8 + h];
  }
  v.x /= d; v.y /= d; v.z /= d; v.w /= d;
  ((f32x4*)out)[t] = v;
}

extern "C" void kernel_launch(void* const* d_in, const int* in_sizes, int n_in,
                              void* d_out, int out_size, void* d_ws, size_t ws_size,
                              hipStream_t stream) {
  const float* x    = (const float*)d_in[0];
  const int*   adj  = (const int*)d_in[1];
  const float* W    = (const float*)d_in[2];
  const float* attn = (const float*)d_in[3];
  float* out = (float*)d_out;
  char* ws = (char*)d_ws;

  // ws layout
  unsigned short* Ab  = (unsigned short*)(ws);                 // 32 MB   adj bf16
  unsigned short* GTp = (unsigned short*)(ws + 33554432);      // 4.5 MB  G^T
  unsigned short* XB  = (unsigned short*)(ws + 38273024);      // 2 MB    x bf16
  unsigned short* WT  = (unsigned short*)(ws + 40370176);      // 256 KB  W^T bf16
  float*          DEN = (float*)(ws + 40632320);               // 512 KB  denom (4 splits)
  float*          NUMX = (float*)(ws + 41156608);              // up to 24 MB partials

  int S = 1;
  if (ws_size >= 41156608ull + 3ull * NUM_STRIDE * 4 + 65536) S = 4;
  else if (ws_size >= 41156608ull + 1ull * NUM_STRIDE * 4 + 65536) S = 2;

  k_small<<<768, 512, 0, stream>>>(x, W, XB, WT);
  k_fat  <<<4352, 512, 0, stream>>>(adj, Ab, XB, WT, attn, GTp);
  dim3 ggrid(288, S);
  k_gemm <<<ggrid, 256, 0, stream>>>(Ab, GTp, out, NUMX, DEN, 4096 / S);
  k_final<<<2048, 256, 0, stream>>>(out, NUMX, DEN, S);
}